// Round 8
// baseline (143.744 us; speedup 1.0000x reference)
//
#include <hip/hip_runtime.h>
#include <math.h>

#define N_TOTAL 8192
#define HALF    4096
#define EMBED   192
#define BT      128                 // block tile (128x128 pairs)
#define NT      (N_TOTAL / BT)      // 64
#define NBLK    (NT * (NT + 1) / 2) // 2080 upper-triangle blocks
#define KCE     64                  // K chunk elems; 3 chunks, single-buffered
#define NCH     (EMBED / KCE)       // 3
#define NPREP   256                 // prep blocks
#define LOG2E   1.4426950408889634f

typedef short          bf16x8 __attribute__((ext_vector_type(8)));
typedef float          f32x4  __attribute__((ext_vector_type(4)));
typedef unsigned short ushort_t;

// ---------------- ws layout (bytes) ----------------
// [0]       int    counter_prep   (zeroed by 1KB memset each launch)
// [4]       int    counter_mmd
// [8]       float  ccl  ( = log2e / (16*bandwidth) )
// [1024]    float  sq[8192]                  -> 33792
// [33792]   ushort xb[8192*192]   (3 MB)     -> 3179520
// [3179520] float  colpart[256*192]          -> 3376128
// [3376128] double sqpart[256]               -> 3378176
// [3378176] double accpart[2080]             -> 3394816

__device__ __forceinline__ unsigned pack2_bf16(float a, float b) {
    unsigned ua = __float_as_uint(a), ub = __float_as_uint(b);
    unsigned ha = (ua + 0x7FFFu + ((ua >> 16) & 1u)) >> 16;   // RNE
    unsigned hb = (ub + 0x7FFFu + ((ub >> 16) & 1u)) >> 16;
    return ha | (hb << 16);
}

// Pass 1: bf16 convert (total-order) + row sumsq + per-block column/sumsq
// partials; last-arriving block computes the bandwidth constant.
__global__ __launch_bounds__(256) void prep(
    const float* __restrict__ x, ushort_t* __restrict__ xb,
    float* __restrict__ sq, float* __restrict__ colpart,
    double* __restrict__ sqpart, int* __restrict__ counter,
    float* __restrict__ ccl_out) {
    __shared__ float4 lscol[4][48];
    __shared__ double lssq[4];
    __shared__ int    lastflag;
    __shared__ double red[4][2];

    int t = threadIdx.x, b = blockIdx.x;
    int lane = t & 63, w = t >> 6;
    int r = b * 32 + (t >> 3), sub = t & 7;
    int g = (r & 1) ? (HALF + (r >> 1)) : (r >> 1);
    const float* src = x  + (size_t)r * EMBED;
    ushort_t*    dst = xb + (size_t)g * EMBED;

    float  s = 0.f;
    float4 v[6];
#pragma unroll
    for (int m = 0; m < 6; ++m) {
        v[m] = *(const float4*)(src + (sub + 8 * m) * 4);
        s += v[m].x * v[m].x + v[m].y * v[m].y + v[m].z * v[m].z + v[m].w * v[m].w;
    }
#pragma unroll
    for (int m = 0; m < 6; ++m) {
        uint2 o;
        o.x = pack2_bf16(v[m].x, v[m].y);
        o.y = pack2_bf16(v[m].z, v[m].w);
        *(uint2*)(dst + (sub + 8 * m) * 4) = o;
    }
    // row sumsq: reduce over lane bits 0..2 (8 subs of one row)
    s += __shfl_xor(s, 1, 64);
    s += __shfl_xor(s, 2, 64);
    s += __shfl_xor(s, 4, 64);
    if (sub == 0) sq[g] = s;
    // column partials: butterfly over lane bits 3..5 (the wave's 8 rows)
#pragma unroll
    for (int m = 0; m < 6; ++m) {
#pragma unroll
        for (int off = 8; off <= 32; off <<= 1) {
            v[m].x += __shfl_xor(v[m].x, off, 64);
            v[m].y += __shfl_xor(v[m].y, off, 64);
            v[m].z += __shfl_xor(v[m].z, off, 64);
            v[m].w += __shfl_xor(v[m].w, off, 64);
        }
    }
    if (lane < 8) {
#pragma unroll
        for (int m = 0; m < 6; ++m) lscol[w][lane + 8 * m] = v[m];
    }
    // wave total of row sums (lanes with sub==0 carry row totals)
    float bs = (sub == 0) ? s : 0.f;
    bs += __shfl_xor(bs, 8, 64);
    bs += __shfl_xor(bs, 16, 64);
    bs += __shfl_xor(bs, 32, 64);
    if (lane == 0) lssq[w] = (double)bs;
    __syncthreads();
    if (t < 48) {
        float4 a = lscol[0][t], b4 = lscol[1][t], c4 = lscol[2][t], d4 = lscol[3][t];
        float4 o;
        o.x = a.x + b4.x + c4.x + d4.x;
        o.y = a.y + b4.y + c4.y + d4.y;
        o.z = a.z + b4.z + c4.z + d4.z;
        o.w = a.w + b4.w + c4.w + d4.w;
        ((float4*)colpart)[b * 48 + t] = o;
    }
    if (t == 0) sqpart[b] = lssq[0] + lssq[1] + lssq[2] + lssq[3];

    __threadfence();
    __syncthreads();
    if (t == 0) {
        int old = atomicAdd(counter, 1);
        lastflag = (old == NPREP - 1);
    }
    __syncthreads();
    if (!lastflag) return;
    __threadfence();   // acquire

    double p = 0.0;
    if (t < EMBED) {
        float cs = 0.f;
        for (int bb = 0; bb < NPREP; ++bb) cs += colpart[bb * EMBED + t];
        p = (double)cs * (double)cs;
    }
    double z = sqpart[t];
#pragma unroll
    for (int off = 32; off; off >>= 1) {
        p += __shfl_down(p, off, 64);
        z += __shfl_down(z, off, 64);
    }
    if (lane == 0) { red[w][0] = p; red[w][1] = z; }
    __syncthreads();
    if (t == 0) {
        double P = red[0][0] + red[1][0] + red[2][0] + red[3][0];
        double S = red[0][1] + red[1][1] + red[2][1] + red[3][1];
        double n = (double)N_TOTAL;
        double sumL2 = 2.0 * n * S - 2.0 * P;
        double bw = sumL2 / (n * n - n) / 4.0;
        *ccl_out = (float)((double)LOG2E / (16.0 * bw));
    }
}

// Pass 2: MFMA Gram + fused 5-scale Gaussian epilogue + folded final
// reduction. R4's exact proven structure: T=128, KC=64, single-buffered,
// 128B LDS rows with XOR-swizzled 16B chunks (measured 0 conflicts),
// 16x16x32 MFMAs, issue->barrier->compute->barrier per chunk. LDS trimmed
// to EXACTLY 32768 B (wred/lastflag aliased into As after last barrier)
// -> 5 blocks/CU.
__global__ __launch_bounds__(256, 4) void mmd_mfma(
    const ushort_t* __restrict__ xb, const float* __restrict__ sq,
    const float* __restrict__ ccl_p, double* __restrict__ accpart,
    int* __restrict__ counter, float* __restrict__ out) {
    int id = blockIdx.x, bi = 0;
    while (id >= NT - bi) { id -= NT - bi; ++bi; }
    int bj = bi + id;
    int I0 = bi * BT, J0 = bj * BT;

    __shared__ ushort_t As[BT][KCE];   // 16 KB
    __shared__ ushort_t Bs[BT][KCE];   // 16 KB  (total exactly 32768 B)
    double* wred     = (double*)&As[0][0];            // alias: safe after final barrier
    int*    lastflag = (int*)((char*)&As[0][0] + 64); // alias

    int t = threadIdx.x, lane = t & 63, wid = t >> 6;
    int wy = (wid >> 1) * 64, wx = (wid & 1) * 64;
    int lo = lane & 15, kg = lane >> 4;

    // staging: each issue = 8 rows x 128B (1KB); lane -> row lane>>3,
    // source 16B-chunk (lane&7)^srow so LDS[r][p] = global[r][p ^ (r&7)]
    int srow = lane >> 3;
    int sch  = (lane & 7) ^ srow;

    f32x4 acc[4][4];
#pragma unroll
    for (int i = 0; i < 4; ++i)
#pragma unroll
        for (int j = 0; j < 4; ++j) acc[i][j] = (f32x4)(0.f);

    const float ccl = *ccl_p;

    for (int c = 0; c < NCH; ++c) {
        int kc0 = c * KCE;
#pragma unroll
        for (int qi = 0; qi < 8; ++qi) {
            int q    = wid * 8 + qi;       // 32 issues: 16 A + 16 B
            int r0   = (q & 15) * 8;
            int isB  = q >> 4;
            int grow = (isB ? J0 : I0) + r0 + srow;
            const ushort_t* gp = xb + (size_t)grow * EMBED + kc0 + sch * 8;
            ushort_t* lp = (isB ? &Bs[0][0] : &As[0][0]) + r0 * KCE;
            __builtin_amdgcn_global_load_lds(
                (const __attribute__((address_space(1))) void*)gp,
                (__attribute__((address_space(3))) void*)lp, 16, 0, 0);
        }
        __syncthreads();                   // DMA(c) drained: data ready
#pragma unroll
        for (int kh = 0; kh < 2; ++kh) {
            int ch = ((kh << 2) + kg) ^ (lo & 7);   // un-swizzle at read
            bf16x8 a[4], b[4];
#pragma unroll
            for (int i = 0; i < 4; ++i) a[i] = *(const bf16x8*)&As[wy + i * 16 + lo][ch * 8];
#pragma unroll
            for (int j = 0; j < 4; ++j) b[j] = *(const bf16x8*)&Bs[wx + j * 16 + lo][ch * 8];
#pragma unroll
            for (int i = 0; i < 4; ++i)
#pragma unroll
                for (int j = 0; j < 4; ++j)
                    acc[i][j] = __builtin_amdgcn_mfma_f32_16x16x32_bf16(a[i], b[j], acc[i][j], 0, 0, 0);
        }
        __syncthreads();                   // protect buffer for next DMA
    }

    // epilogue: C/D layout col=lane&15, row=(lane>>4)*4+reg (m89-verified)
    int gi0 = I0 + wy + kg * 4;
    int gj0 = J0 + wx + lo;
    float nsic[4][4], nsjc[4];
#pragma unroll
    for (int i = 0; i < 4; ++i)
#pragma unroll
        for (int r = 0; r < 4; ++r) nsic[i][r] = -ccl * sq[gi0 + i * 16 + r];
#pragma unroll
    for (int j = 0; j < 4; ++j) nsjc[j] = -ccl * sq[gj0 + j * 16];
    const float cc2 = 2.f * ccl;

    float sgn  = ((bi < NT / 2) == (bj < NT / 2)) ? 1.f : -1.f;
    float tsum = 0.f;
    if (bi != bj) {
#pragma unroll
        for (int i = 0; i < 4; ++i)
#pragma unroll
            for (int j = 0; j < 4; ++j)
#pragma unroll
                for (int r = 0; r < 4; ++r) {
                    float arg = fminf(fmaf(cc2, acc[i][j][r], nsic[i][r]) + nsjc[j], 0.f);
                    float u   = __builtin_amdgcn_exp2f(arg);
                    float u2 = u * u, u4 = u2 * u2, u8 = u4 * u4;
                    tsum += ((u + u2) + u4) + fmaf(u8, u8, u8);
                }
        tsum *= 2.f;
    } else {
#pragma unroll
        for (int i = 0; i < 4; ++i)
#pragma unroll
            for (int j = 0; j < 4; ++j)
#pragma unroll
                for (int r = 0; r < 4; ++r) {
                    int gi = gi0 + i * 16 + r, gj = gj0 + j * 16;
                    float w = (gi < gj) ? 2.f : ((gi == gj) ? 1.f : 0.f);
                    float arg = fminf(fmaf(cc2, acc[i][j][r], nsic[i][r]) + nsjc[j], 0.f);
                    float u   = __builtin_amdgcn_exp2f(arg);
                    float u2 = u * u, u4 = u2 * u2, u8 = u4 * u4;
                    tsum += w * (((u + u2) + u4) + fmaf(u8, u8, u8));
                }
    }
    tsum *= sgn;

#pragma unroll
    for (int off = 32; off; off >>= 1) tsum += __shfl_down(tsum, off, 64);
    if (lane == 0) wred[wid] = (double)tsum;   // into As alias (reads all done)
    __syncthreads();
    if (t == 0) {
        accpart[blockIdx.x] = wred[0] + wred[1] + wred[2] + wred[3];
        __threadfence();                       // release partial
        int old = atomicAdd(counter, 1);
        *lastflag = (old == NBLK - 1);
    }
    __syncthreads();
    if (!*lastflag) return;
    __threadfence();                           // acquire peers' partials

    double s = 0.0;
    for (int i = t; i < NBLK; i += 256) s += accpart[i];
#pragma unroll
    for (int off = 32; off; off >>= 1) s += __shfl_down(s, off, 64);
    __syncthreads();
    if (lane == 0) wred[t >> 6] = s;
    __syncthreads();
    if (t == 0) {
        double tot = wred[0] + wred[1] + wred[2] + wred[3];
        out[0] = (float)(tot / ((double)HALF * (double)HALF));
    }
}

extern "C" void kernel_launch(void* const* d_in, const int* in_sizes, int n_in,
                              void* d_out, int out_size, void* d_ws, size_t ws_size,
                              hipStream_t stream) {
    const float* x = (const float*)d_in[0];   // label / genre_label unused

    int*      d_cprep   = (int*)d_ws;
    int*      d_cmmd    = (int*)d_ws + 1;
    float*    d_ccl     = (float*)((char*)d_ws + 8);
    float*    d_sq      = (float*)((char*)d_ws + 1024);
    ushort_t* d_xb      = (ushort_t*)((char*)d_ws + 33792);
    float*    d_colpart = (float*)((char*)d_ws + 3179520);
    double*   d_sqpart  = (double*)((char*)d_ws + 3376128);
    double*   d_accpart = (double*)((char*)d_ws + 3378176);

    hipMemsetAsync(d_ws, 0, 1024, stream);   // zero counters

    prep<<<NPREP, 256, 0, stream>>>(x, d_xb, d_sq, d_colpart, d_sqpart,
                                    d_cprep, d_ccl);
    mmd_mfma<<<NBLK, 256, 0, stream>>>(d_xb, d_sq, d_ccl, d_accpart,
                                       d_cmmd, (float*)d_out);
}

// Round 9
// 132.266 us; speedup vs baseline: 1.0868x; 1.0868x over previous
//
#include <hip/hip_runtime.h>
#include <math.h>

#define N_TOTAL 8192
#define HALF    4096
#define EMBED   192
#define BT      128                 // block tile (128x128 pairs)
#define NT      (N_TOTAL / BT)      // 64
#define NBLK    (NT * (NT + 1) / 2) // 2080 upper-triangle blocks
#define KCE     64                  // K chunk elems; 3 chunks, A double-buffered
#define NCH     (EMBED / KCE)       // 3
#define NPREP   256                 // prep blocks
#define LOG2E   1.4426950408889634f

typedef short          bf16x8 __attribute__((ext_vector_type(8)));
typedef float          f32x4  __attribute__((ext_vector_type(4)));
typedef unsigned short ushort_t;

// ---------------- ws layout (bytes) ----------------
// [0]       int    counter_prep   (zeroed by memset each launch)
// [8]       float  ccl  ( = log2e / (16*bandwidth) )
// [1024]    float  sq[8192]                  -> 33792
// [33792]   ushort xb[8192*192]   (3 MB)     -> 3179520
// [3179520] float  colpart[256*192]          -> 3376128
// [3376128] double sqpart[256]               -> 3378176
// [3378176] double accpart[2080]             -> 3394816

__device__ __forceinline__ unsigned pack2_bf16(float a, float b) {
    unsigned ua = __float_as_uint(a), ub = __float_as_uint(b);
    unsigned ha = (ua + 0x7FFFu + ((ua >> 16) & 1u)) >> 16;   // RNE
    unsigned hb = (ub + 0x7FFFu + ((ub >> 16) & 1u)) >> 16;
    return ha | (hb << 16);
}

// Pass 1: bf16 convert (total-order) + row sumsq + per-block column/sumsq
// partials; last-arriving block computes the bandwidth constant.
__global__ __launch_bounds__(256) void prep(
    const float* __restrict__ x, ushort_t* __restrict__ xb,
    float* __restrict__ sq, float* __restrict__ colpart,
    double* __restrict__ sqpart, int* __restrict__ counter,
    float* __restrict__ ccl_out) {
    __shared__ float4 lscol[4][48];
    __shared__ double lssq[4];
    __shared__ int    lastflag;
    __shared__ double red[4][2];

    int t = threadIdx.x, b = blockIdx.x;
    int lane = t & 63, w = t >> 6;
    int r = b * 32 + (t >> 3), sub = t & 7;
    int g = (r & 1) ? (HALF + (r >> 1)) : (r >> 1);
    const float* src = x  + (size_t)r * EMBED;
    ushort_t*    dst = xb + (size_t)g * EMBED;

    float  s = 0.f;
    float4 v[6];
#pragma unroll
    for (int m = 0; m < 6; ++m) {
        v[m] = *(const float4*)(src + (sub + 8 * m) * 4);
        s += v[m].x * v[m].x + v[m].y * v[m].y + v[m].z * v[m].z + v[m].w * v[m].w;
    }
#pragma unroll
    for (int m = 0; m < 6; ++m) {
        uint2 o;
        o.x = pack2_bf16(v[m].x, v[m].y);
        o.y = pack2_bf16(v[m].z, v[m].w);
        *(uint2*)(dst + (sub + 8 * m) * 4) = o;
    }
    // row sumsq: reduce over lane bits 0..2 (8 subs of one row)
    s += __shfl_xor(s, 1, 64);
    s += __shfl_xor(s, 2, 64);
    s += __shfl_xor(s, 4, 64);
    if (sub == 0) sq[g] = s;
    // column partials: butterfly over lane bits 3..5 (the wave's 8 rows)
#pragma unroll
    for (int m = 0; m < 6; ++m) {
#pragma unroll
        for (int off = 8; off <= 32; off <<= 1) {
            v[m].x += __shfl_xor(v[m].x, off, 64);
            v[m].y += __shfl_xor(v[m].y, off, 64);
            v[m].z += __shfl_xor(v[m].z, off, 64);
            v[m].w += __shfl_xor(v[m].w, off, 64);
        }
    }
    if (lane < 8) {
#pragma unroll
        for (int m = 0; m < 6; ++m) lscol[w][lane + 8 * m] = v[m];
    }
    // wave total of row sums (lanes with sub==0 carry row totals)
    float bs = (sub == 0) ? s : 0.f;
    bs += __shfl_xor(bs, 8, 64);
    bs += __shfl_xor(bs, 16, 64);
    bs += __shfl_xor(bs, 32, 64);
    if (lane == 0) lssq[w] = (double)bs;
    __syncthreads();
    if (t < 48) {
        float4 a = lscol[0][t], b4 = lscol[1][t], c4 = lscol[2][t], d4 = lscol[3][t];
        float4 o;
        o.x = a.x + b4.x + c4.x + d4.x;
        o.y = a.y + b4.y + c4.y + d4.y;
        o.z = a.z + b4.z + c4.z + d4.z;
        o.w = a.w + b4.w + c4.w + d4.w;
        ((float4*)colpart)[b * 48 + t] = o;
    }
    if (t == 0) sqpart[b] = lssq[0] + lssq[1] + lssq[2] + lssq[3];

    __threadfence();
    __syncthreads();
    if (t == 0) {
        int old = atomicAdd(counter, 1);
        lastflag = (old == NPREP - 1);
    }
    __syncthreads();
    if (!lastflag) return;
    __threadfence();   // acquire

    double p = 0.0;
    if (t < EMBED) {
        float cs = 0.f;
        for (int bb = 0; bb < NPREP; ++bb) cs += colpart[bb * EMBED + t];
        p = (double)cs * (double)cs;
    }
    double z = sqpart[t];
#pragma unroll
    for (int off = 32; off; off >>= 1) {
        p += __shfl_down(p, off, 64);
        z += __shfl_down(z, off, 64);
    }
    if (lane == 0) { red[w][0] = p; red[w][1] = z; }
    __syncthreads();
    if (t == 0) {
        double P = red[0][0] + red[1][0] + red[2][0] + red[3][0];
        double S = red[0][1] + red[1][1] + red[2][1] + red[3][1];
        double n = (double)N_TOTAL;
        double sumL2 = 2.0 * n * S - 2.0 * P;
        double bw = sumL2 / (n * n - n) / 4.0;
        *ccl_out = (float)((double)LOG2E / (16.0 * bw));
    }
}

// Pass 2: MFMA Gram + fused 5-scale Gaussian epilogue.
// A staged via async DMA into double-buffered LDS (2x16KB, XOR-swizzled 128B
// rows — R4's measured-0-conflict layout); DMA(c+1) issued after barrier(c),
// before compute(c) -> 3 barriers/block, each draining a DMA that had a full
// compute phase in flight. B read DIRECTLY from global (L2-resident xb):
// each wave b-load = 16 rows x 64 contiguous bytes, perfectly coalesced.
// wred aliased into As[1] (dead after the c=2 barrier) -> LDS exactly 32768 B.
__global__ __launch_bounds__(256, 4) void mmd_mfma(
    const ushort_t* __restrict__ xb, const float* __restrict__ sq,
    const float* __restrict__ ccl_p, double* __restrict__ accpart) {
    int id = blockIdx.x, bi = 0;
    while (id >= NT - bi) { id -= NT - bi; ++bi; }
    int bj = bi + id;
    int I0 = bi * BT, J0 = bj * BT;

    __shared__ ushort_t As[2][BT][KCE];              // 32768 B total
    double* wred = (double*)&As[1][0][0];            // alias: As[1] last read at chunk 1

    int t = threadIdx.x, lane = t & 63, wid = t >> 6;
    int wy = (wid >> 1) * 64, wx = (wid & 1) * 64;
    int lo = lane & 15, kg = lane >> 4;

    // A staging: each issue = 8 rows x 128B (1KB); lane -> row lane>>3,
    // source 16B-chunk (lane&7)^srow so LDS[r][p] = global[r][p ^ (r&7)]
    int srow = lane >> 3;
    int sch  = (lane & 7) ^ srow;

    // B direct-load base: lane (lo,kg) covers B[col=lo][k = kg*8 + e]
    const ushort_t* bbase = xb + (size_t)(J0 + wx + lo) * EMBED + kg * 8;

    f32x4 acc[4][4];
#pragma unroll
    for (int i = 0; i < 4; ++i)
#pragma unroll
        for (int j = 0; j < 4; ++j) acc[i][j] = (f32x4)(0.f);

    const float ccl = *ccl_p;

    auto issueA = [&](int c, int buf) {
        int kc0 = c * KCE;
#pragma unroll
        for (int qi = 0; qi < 4; ++qi) {
            int q    = wid * 4 + qi;       // 16 issues, A only
            int r0   = q * 8;
            int grow = I0 + r0 + srow;
            const ushort_t* gp = xb + (size_t)grow * EMBED + kc0 + sch * 8;
            ushort_t* lp = &As[buf][0][0] + r0 * KCE;
            __builtin_amdgcn_global_load_lds(
                (const __attribute__((address_space(1))) void*)gp,
                (__attribute__((address_space(3))) void*)lp, 16, 0, 0);
        }
    };

    issueA(0, 0);
#pragma unroll
    for (int c = 0; c < NCH; ++c) {
        int buf = c & 1;
        __syncthreads();                           // DMA(c) drained, buf^1 free
        if (c + 1 < NCH) issueA(c + 1, buf ^ 1);   // prefetch next A chunk
        // B fragments for this chunk: 8 independent coalesced 16B loads
        bf16x8 bb[2][4];
#pragma unroll
        for (int kh = 0; kh < 2; ++kh)
#pragma unroll
            for (int j = 0; j < 4; ++j)
                bb[kh][j] = *(const bf16x8*)(bbase + j * 16 * EMBED + c * KCE + kh * 32);
#pragma unroll
        for (int kh = 0; kh < 2; ++kh) {
            int ch = ((kh << 2) + kg) ^ (lo & 7);   // un-swizzle A at read
            bf16x8 a[4];
#pragma unroll
            for (int i = 0; i < 4; ++i) a[i] = *(const bf16x8*)&As[buf][wy + i * 16 + lo][ch * 8];
#pragma unroll
            for (int i = 0; i < 4; ++i)
#pragma unroll
                for (int j = 0; j < 4; ++j)
                    acc[i][j] = __builtin_amdgcn_mfma_f32_16x16x32_bf16(a[i], bb[kh][j], acc[i][j], 0, 0, 0);
        }
    }

    // epilogue: C/D layout col=lane&15, row=(lane>>4)*4+reg (m89-verified)
    int gi0 = I0 + wy + kg * 4;
    int gj0 = J0 + wx + lo;
    float nsic[4][4], nsjc[4];
#pragma unroll
    for (int i = 0; i < 4; ++i)
#pragma unroll
        for (int r = 0; r < 4; ++r) nsic[i][r] = -ccl * sq[gi0 + i * 16 + r];
#pragma unroll
    for (int j = 0; j < 4; ++j) nsjc[j] = -ccl * sq[gj0 + j * 16];
    const float cc2 = 2.f * ccl;

    float sgn  = ((bi < NT / 2) == (bj < NT / 2)) ? 1.f : -1.f;
    float tsum = 0.f;
    if (bi != bj) {
#pragma unroll
        for (int i = 0; i < 4; ++i)
#pragma unroll
            for (int j = 0; j < 4; ++j)
#pragma unroll
                for (int r = 0; r < 4; ++r) {
                    float arg = fminf(fmaf(cc2, acc[i][j][r], nsic[i][r]) + nsjc[j], 0.f);
                    float u   = __builtin_amdgcn_exp2f(arg);
                    float u2 = u * u, u4 = u2 * u2, u8 = u4 * u4;
                    tsum += ((u + u2) + u4) + fmaf(u8, u8, u8);
                }
        tsum *= 2.f;
    } else {
#pragma unroll
        for (int i = 0; i < 4; ++i)
#pragma unroll
            for (int j = 0; j < 4; ++j)
#pragma unroll
                for (int r = 0; r < 4; ++r) {
                    int gi = gi0 + i * 16 + r, gj = gj0 + j * 16;
                    float w = (gi < gj) ? 2.f : ((gi == gj) ? 1.f : 0.f);
                    float arg = fminf(fmaf(cc2, acc[i][j][r], nsic[i][r]) + nsjc[j], 0.f);
                    float u   = __builtin_amdgcn_exp2f(arg);
                    float u2 = u * u, u4 = u2 * u2, u8 = u4 * u4;
                    tsum += w * (((u + u2) + u4) + fmaf(u8, u8, u8));
                }
    }
    tsum *= sgn;

#pragma unroll
    for (int off = 32; off; off >>= 1) tsum += __shfl_down(tsum, off, 64);
    if (lane == 0) wred[wid] = (double)tsum;   // As[1] alias — dead since c=2 barrier
    __syncthreads();
    if (t == 0) accpart[blockIdx.x] = wred[0] + wred[1] + wred[2] + wred[3];
}

// Pass 3: reduce 2080 block partials -> loss (separate tiny dispatch:
// folding this into mmd via counter+fence measured +17 us — R5/R6/R8).
__global__ __launch_bounds__(256) void finalize_loss(
    const double* __restrict__ accpart, float* __restrict__ out) {
    __shared__ double red[4];
    int t = threadIdx.x, lane = t & 63, w = t >> 6;
    double s = 0.0;
    for (int i = t; i < NBLK; i += 256) s += accpart[i];
#pragma unroll
    for (int off = 32; off; off >>= 1) s += __shfl_down(s, off, 64);
    if (lane == 0) red[w] = s;
    __syncthreads();
    if (t == 0) {
        double tot = red[0] + red[1] + red[2] + red[3];
        out[0] = (float)(tot / ((double)HALF * (double)HALF));
    }
}

extern "C" void kernel_launch(void* const* d_in, const int* in_sizes, int n_in,
                              void* d_out, int out_size, void* d_ws, size_t ws_size,
                              hipStream_t stream) {
    const float* x = (const float*)d_in[0];   // label / genre_label unused

    int*      d_cprep   = (int*)d_ws;
    float*    d_ccl     = (float*)((char*)d_ws + 8);
    float*    d_sq      = (float*)((char*)d_ws + 1024);
    ushort_t* d_xb      = (ushort_t*)((char*)d_ws + 33792);
    float*    d_colpart = (float*)((char*)d_ws + 3179520);
    double*   d_sqpart  = (double*)((char*)d_ws + 3376128);
    double*   d_accpart = (double*)((char*)d_ws + 3378176);

    hipMemsetAsync(d_ws, 0, 1024, stream);   // zero counter

    prep<<<NPREP, 256, 0, stream>>>(x, d_xb, d_sq, d_colpart, d_sqpart,
                                    d_cprep, d_ccl);
    mmd_mfma<<<NBLK, 256, 0, stream>>>(d_xb, d_sq, d_ccl, d_accpart);
    finalize_loss<<<1, 256, 0, stream>>>(d_accpart, (float*)d_out);
}